// Round 3
// baseline (463.587 us; speedup 1.0000x reference)
//
#include <hip/hip_runtime.h>
#include <hip/hip_bf16.h>

typedef __bf16 bf16;
typedef __bf16 bf16x4 __attribute__((ext_vector_type(4)));
typedef __bf16 bf16x8 __attribute__((ext_vector_type(8)));
typedef float  f32x4  __attribute__((ext_vector_type(4)));
typedef float  f32x8  __attribute__((ext_vector_type(8)));

#define MFMA16(A,B,C) __builtin_amdgcn_mfma_f32_16x16x32_bf16((A),(B),(C),0,0,0)

constexpr int   N_TOK = 49;
constexpr int   DIM_C = 256;
constexpr float SCALE = 0.17677669529663687f;   // 32^-0.5

// ---- LDS layout (bf16 element offsets) ----
// [0, 25088): QK region — 49 rows x 512 (cols 0-255 Q scaled, 256-511 K), XOR-swizzled.
//             Stage-2 overlays each wave's P tile onto its own dead 32-col Q/K stripes.
// [25088, 39424): vT region — [256 d][56 j], stride 56 (112 B, odd-bank-spread, no XOR).
//             XB (x bf16 [49][256], swizzled) overlays its first 25088 B during stage 0/1.
//             ao overlays per-head 1792-elem stripes (stride 36, b64-friendly) during PV.
// [39424, 39936): overread pad (zeroed) — MFMA row/col padding reads land here finitely.
constexpr int VT         = 25088;                 // elems
constexpr int PAD_BASE   = VT + 256 * 56;         // 39424
constexpr int SMEM_ELEMS = PAD_BASE + 512;        // 39936 elems = 79,872 B (2 blocks/CU)

// ws layout (bytes)
constexpr size_t CB_BYTES    = 64ull * 8 * 64 * 64 * 4;   // 8 MB
constexpr int    QKVW_ELEMS  = 768 * 256;
constexpr int    PROJW_ELEMS = 256 * 256;

__global__ __launch_bounds__(256) void build_cb_kernel(
    const float* __restrict__ bias_table, const float* __restrict__ mask,
    const int* __restrict__ rel_index, float* __restrict__ cb) {
  int idx = blockIdx.x * 256 + threadIdx.x;          // [64 w][8 h][64 m][64 j]
  int j = idx & 63, m = (idx >> 6) & 63, h = (idx >> 12) & 7, w = idx >> 15;
  float v = 0.f;
  if (j < N_TOK && m < N_TOK)
    v = bias_table[rel_index[m * 49 + j] * 8 + h] + mask[(w * 49 + m) * 49 + j];
  cb[idx] = v;
}

__global__ __launch_bounds__(256) void cvt_w_kernel(
    const float* __restrict__ qkv_w, const float* __restrict__ proj_w,
    bf16* __restrict__ qkv_wb, bf16* __restrict__ proj_wb) {
  int i = blockIdx.x * 256 + threadIdx.x;
  if (i < QKVW_ELEMS) qkv_wb[i] = (bf16)qkv_w[i];
  else                proj_wb[i - QKVW_ELEMS] = (bf16)proj_w[i - QKVW_ELEMS];
}

__global__ __launch_bounds__(512, 4) void win_attn_kernel(
    const float* __restrict__ x, const bf16* __restrict__ qkv_wb,
    const float* __restrict__ qkv_b, const bf16* __restrict__ proj_wb,
    const float* __restrict__ proj_b, const float* __restrict__ cb,
    float* __restrict__ out) {
  __shared__ bf16 smem[SMEM_ELEMS];

  const int beta  = blockIdx.x;
  const int w_idx = beta >> 6;          // 64 consecutive blocks share one mask slice (L2)
  const int img   = beta & 63;
  const int b     = img * 64 + w_idx;
  const int tid   = threadIdx.x;
  const int wv    = tid >> 6;           // wave id; also head id in stage 2
  const int l     = tid & 63;
  const int l15   = l & 15, lgp = l >> 4;

  const f32x4 fzero = {0.f, 0.f, 0.f, 0.f};
  const bf16x8 bzero = {(bf16)0.f,(bf16)0.f,(bf16)0.f,(bf16)0.f,
                        (bf16)0.f,(bf16)0.f,(bf16)0.f,(bf16)0.f};

  // zero the overread pad + vT pad cols j in [49,56) of rows 224..255
  // (rows <224 get finite stale-XB data there; all other overreads land on
  //  finite written data — any finite value is killed by P=0 on the A side)
  if (tid < 512) smem[PAD_BASE + tid] = (bf16)0.f;
  if (tid < 224) {
    int d = 224 + tid / 7, j = 49 + tid % 7;
    smem[VT + d * 56 + j] = (bf16)0.f;
  }

  // ---------------- stage 0: x tile f32 -> XB (bf16, swizzled, over vT) ----
  const float* xg = x + (size_t)b * (N_TOK * DIM_C);
  for (int c = tid; c < (N_TOK * DIM_C / 8); c += 512) {
    int m = c >> 5, k0 = (c & 31) * 8;
    f32x8 f = *reinterpret_cast<const f32x8*>(xg + m * 256 + k0);
    bf16x8 v;
#pragma unroll
    for (int e = 0; e < 8; ++e) v[e] = (bf16)f[e];
    *reinterpret_cast<bf16x8*>(&smem[VT + m * 256 + (k0 ^ ((m & 7) << 3))]) = v;
  }
  __syncthreads();

  // ---------------- stage 1a: Q,K tiles (wave wv: n-tiles 4wv..4wv+3) ------
  {
    f32x4 acc[4][4];
#pragma unroll
    for (int i = 0; i < 4; ++i)
      for (int mt = 0; mt < 4; ++mt) acc[i][mt] = fzero;
    for (int k0 = 0; k0 < 8; ++k0) {
      const int kk = k0 * 32 + lgp * 8;
      bf16x8 A[4];
#pragma unroll
      for (int mt = 0; mt < 4; ++mt) {
        int m = mt * 16 + l15;
        A[mt] = (m < N_TOK)
            ? *reinterpret_cast<const bf16x8*>(
                  &smem[VT + m * 256 + (kk ^ ((m & 7) << 3))])
            : bzero;
      }
#pragma unroll
      for (int i = 0; i < 4; ++i) {
        int c = (4 * wv + i) * 16 + l15;
        bf16x8 B = *reinterpret_cast<const bf16x8*>(qkv_wb + c * DIM_C + kk);
#pragma unroll
        for (int mt = 0; mt < 4; ++mt) acc[i][mt] = MFMA16(A[mt], B, acc[i][mt]);
      }
    }
#pragma unroll
    for (int i = 0; i < 4; ++i) {
      int c = (4 * wv + i) * 16 + l15;
      float qb = qkv_b[c];
      float sc = (c < 256) ? SCALE : 1.0f;     // pre-scale Q
#pragma unroll
      for (int mt = 0; mt < 4; ++mt) {
#pragma unroll
        for (int r = 0; r < 4; ++r) {
          int m = mt * 16 + lgp * 4 + r;
          if (m < N_TOK)
            smem[m * 512 + (c ^ ((m & 7) << 3))] = (bf16)((acc[i][mt][r] + qb) * sc);
        }
      }
    }
  }

  // ---------------- stage 1b: V tiles (accs held across barrier) ----------
  {
    f32x4 accv[2][4];
#pragma unroll
    for (int i = 0; i < 2; ++i)
      for (int mt = 0; mt < 4; ++mt) accv[i][mt] = fzero;
    for (int k0 = 0; k0 < 8; ++k0) {
      const int kk = k0 * 32 + lgp * 8;
      bf16x8 A[4];
#pragma unroll
      for (int mt = 0; mt < 4; ++mt) {
        int m = mt * 16 + l15;
        A[mt] = (m < N_TOK)
            ? *reinterpret_cast<const bf16x8*>(
                  &smem[VT + m * 256 + (kk ^ ((m & 7) << 3))])
            : bzero;
      }
#pragma unroll
      for (int i = 0; i < 2; ++i) {
        int c = (32 + 2 * wv + i) * 16 + l15;
        bf16x8 B = *reinterpret_cast<const bf16x8*>(qkv_wb + c * DIM_C + kk);
#pragma unroll
        for (int mt = 0; mt < 4; ++mt) accv[i][mt] = MFMA16(A[mt], B, accv[i][mt]);
      }
    }
    __syncthreads();   // all XB reads done; vT region may now be overwritten
#pragma unroll
    for (int i = 0; i < 2; ++i) {
      int c = (32 + 2 * wv + i) * 16 + l15;
      int d = c - 512;
      float qb = qkv_b[c];
#pragma unroll
      for (int mt = 0; mt < 4; ++mt) {
#pragma unroll
        for (int r = 0; r < 4; ++r) {
          int m = mt * 16 + lgp * 4 + r;
          if (m < N_TOK) smem[VT + d * 56 + m] = (bf16)(accv[i][mt][r] + qb);
        }
      }
    }
  }
  __syncthreads();

  // ---------------- stage 2 (wave = head h): S, softmax, PV ---------------
  const int h = wv;
  float rinv[4][4];
  {
    // hoist K fragments (their stripe is clobbered by P writes below)
    bf16x8 Bk[4];
#pragma unroll
    for (int jt = 0; jt < 4; ++jt) {
      int n = jt * 16 + l15;
      Bk[jt] = *reinterpret_cast<const bf16x8*>(
          &smem[n * 512 + ((256 + h * 32 + lgp * 8) ^ ((n & 7) << 3))]);
    }
    const float* cbp = cb + ((size_t)(w_idx * 8 + h)) * 64 * 64;
#pragma unroll
    for (int mt = 0; mt < 4; ++mt) {
      int m_a = mt * 16 + l15;
      bf16x8 Aq = *reinterpret_cast<const bf16x8*>(
          &smem[m_a * 512 + ((h * 32 + lgp * 8) ^ ((m_a & 7) << 3))]);
      f32x4 s4[4];
#pragma unroll
      for (int jt = 0; jt < 4; ++jt) s4[jt] = MFMA16(Aq, Bk[jt], fzero);
      float lgt[4][4];
#pragma unroll
      for (int jt = 0; jt < 4; ++jt) {
        int jc = jt * 16 + l15;
#pragma unroll
        for (int r = 0; r < 4; ++r) {
          int m = mt * 16 + lgp * 4 + r;
          float v = s4[jt][r] + cbp[m * 64 + jc];
          if (jc >= N_TOK) v = -3.0e38f;       // pad keys -> exp -> exactly 0
          lgt[jt][r] = v;
        }
      }
#pragma unroll
      for (int r = 0; r < 4; ++r) {
        float mx = fmaxf(fmaxf(lgt[0][r], lgt[1][r]), fmaxf(lgt[2][r], lgt[3][r]));
        mx = fmaxf(mx, __shfl_xor(mx, 1));
        mx = fmaxf(mx, __shfl_xor(mx, 2));
        mx = fmaxf(mx, __shfl_xor(mx, 4));
        mx = fmaxf(mx, __shfl_xor(mx, 8));
        float sum = 0.f;
#pragma unroll
        for (int jt = 0; jt < 4; ++jt) {
          float e = __expf(lgt[jt][r] - mx);
          lgt[jt][r] = e;
          sum += e;
        }
        sum += __shfl_xor(sum, 1);
        sum += __shfl_xor(sum, 2);
        sum += __shfl_xor(sum, 4);
        sum += __shfl_xor(sum, 8);
        rinv[mt][r] = 1.0f / sum;
        int m = mt * 16 + lgp * 4 + r;
        if (m < N_TOK) {
          // P (unnormalized) overlays this wave's dead Q/K column stripes
#pragma unroll
          for (int jt = 0; jt < 4; ++jt) {
            int j = jt * 16 + l15;
            int c = (j < 32) ? (h * 32 + j) : (224 + h * 32 + j);
            smem[m * 512 + (c ^ ((m & 7) << 3))] = (bf16)lgt[jt][r];
          }
        }
      }
    }
  }

  // PV: hoist this head's V fragments, then ao overlays the same vT stripe
  {
    bf16x8 Vf[2][2];
#pragma unroll
    for (int dt = 0; dt < 2; ++dt)
#pragma unroll
      for (int ks = 0; ks < 2; ++ks) {
        int d = h * 32 + dt * 16 + l15;
        Vf[dt][ks] = *reinterpret_cast<const bf16x8*>(
            &smem[VT + d * 56 + ks * 32 + lgp * 8]);
      }
#pragma unroll
    for (int mt = 0; mt < 4; ++mt) {
      int m_a = mt * 16 + l15;
      bf16x8 Ap[2];
#pragma unroll
      for (int ks = 0; ks < 2; ++ks) {
        int c0 = (ks == 0) ? (h * 32 + lgp * 8) : (256 + h * 32 + lgp * 8);
        Ap[ks] = *reinterpret_cast<const bf16x8*>(
            &smem[m_a * 512 + (c0 ^ ((m_a & 7) << 3))]);
      }
#pragma unroll
      for (int dt = 0; dt < 2; ++dt) {
        f32x4 acc = MFMA16(Ap[0], Vf[dt][0], fzero);
        acc = MFMA16(Ap[1], Vf[dt][1], acc);
#pragma unroll
        for (int r = 0; r < 4; ++r) {
          int m = mt * 16 + lgp * 4 + r;
          if (m < N_TOK) {
            int dd = dt * 16 + l15;
            smem[VT + h * 1792 + m * 36 + dd] = (bf16)(acc[r] * rinv[mt][r]);
          }
        }
      }
    }
  }
  __syncthreads();

  // ---------------- stage 3: out = ao @ proj_w^T + proj_b -----------------
  f32x4 acc2[2][4];
#pragma unroll
  for (int ci = 0; ci < 2; ++ci)
    for (int mt = 0; mt < 4; ++mt) acc2[ci][mt] = fzero;
  for (int k0 = 0; k0 < 8; ++k0) {
    bf16x8 A[4];
#pragma unroll
    for (int mt = 0; mt < 4; ++mt) {
      int m = mt * 16 + l15;
      int base = VT + k0 * 1792 + m * 36 + lgp * 8;
      bf16x4 lo = *reinterpret_cast<const bf16x4*>(&smem[base]);
      bf16x4 hi = *reinterpret_cast<const bf16x4*>(&smem[base + 4]);
      A[mt] = __builtin_shufflevector(lo, hi, 0, 1, 2, 3, 4, 5, 6, 7);
    }
#pragma unroll
    for (int ci = 0; ci < 2; ++ci) {
      int n = (wv * 2 + ci) * 16 + l15;
      bf16x8 B = *reinterpret_cast<const bf16x8*>(
          proj_wb + n * DIM_C + k0 * 32 + lgp * 8);
#pragma unroll
      for (int mt = 0; mt < 4; ++mt) acc2[ci][mt] = MFMA16(A[mt], B, acc2[ci][mt]);
    }
  }
  float* ob = out + (size_t)b * (N_TOK * DIM_C);
#pragma unroll
  for (int ci = 0; ci < 2; ++ci) {
    int c = (wv * 2 + ci) * 16 + l15;
    float pb = proj_b[c];
#pragma unroll
    for (int mt = 0; mt < 4; ++mt) {
#pragma unroll
      for (int r = 0; r < 4; ++r) {
        int m = mt * 16 + lgp * 4 + r;
        if (m < N_TOK) ob[m * DIM_C + c] = acc2[ci][mt][r] + pb;
      }
    }
  }
}

extern "C" void kernel_launch(void* const* d_in, const int* in_sizes, int n_in,
                              void* d_out, int out_size, void* d_ws, size_t ws_size,
                              hipStream_t stream) {
  const float* x          = (const float*)d_in[0];
  const float* mask       = (const float*)d_in[1];
  const float* qkv_w      = (const float*)d_in[2];
  const float* qkv_b      = (const float*)d_in[3];
  const float* proj_w     = (const float*)d_in[4];
  const float* proj_b     = (const float*)d_in[5];
  const float* bias_table = (const float*)d_in[6];
  const int*   rel_index  = (const int*)d_in[7];

  float* cb      = (float*)d_ws;
  bf16*  qkv_wb  = (bf16*)((char*)d_ws + CB_BYTES);
  bf16*  proj_wb = (bf16*)((char*)d_ws + CB_BYTES + QKVW_ELEMS * 2);

  hipLaunchKernelGGL(build_cb_kernel, dim3(8192), dim3(256), 0, stream,
                     bias_table, mask, rel_index, cb);
  hipLaunchKernelGGL(cvt_w_kernel, dim3(1024), dim3(256), 0, stream,
                     qkv_w, proj_w, qkv_wb, proj_wb);
  hipLaunchKernelGGL(win_attn_kernel, dim3(4096), dim3(512), 0, stream,
                     x, qkv_wb, qkv_b, proj_wb, proj_b, cb, (float*)d_out);
}

// Round 4
// 427.911 us; speedup vs baseline: 1.0834x; 1.0834x over previous
//
#include <hip/hip_runtime.h>
#include <hip/hip_bf16.h>

typedef __bf16 bf16;
typedef __bf16 bf16x2 __attribute__((ext_vector_type(2)));
typedef __bf16 bf16x8 __attribute__((ext_vector_type(8)));
typedef float  f32x4  __attribute__((ext_vector_type(4)));
typedef float  f32x8  __attribute__((ext_vector_type(8)));

#define MFMA16(A,B,C) __builtin_amdgcn_mfma_f32_16x16x32_bf16((A),(B),(C),0,0,0)

constexpr int   N_TOK = 49;
constexpr int   DIM_C = 256;
constexpr float SCALE = 0.17677669529663687f;   // 32^-0.5

// ---- LDS layout (bf16 element offsets) ----
// [0, 25088): QK region — 49 rows x 512 (cols 0-255 Q scaled, 256-511 K), XOR-swizzled
//             (elem col ^= (row&7)<<3). Stage-2 overlays P[m][j] per wave
//             (j<32 -> Q-stripe col 32h+j ; j>=32 -> K-stripe col 224+32h+j),
//             then ao[m][d] overlays the K-stripe (col 256+32h+d) for stage 3.
// [25088, 39424): vT region [256 d][56 j], no swizzle.
//             XB (x bf16 rows m<49, [m][256], swizzled) overlays it during stage 0/1.
// [39424, 39936): zeroed pad (tail overreads land here).
constexpr int VT         = 25088;
constexpr int PAD_BASE   = VT + 256 * 56;         // 39424
constexpr int SMEM_ELEMS = PAD_BASE + 512;        // 79,872 B -> 2 blocks/CU

// ws layout (bytes)
constexpr size_t CB_BYTES    = 64ull * 8 * 64 * 64 * 4;   // 8 MB
constexpr int    QKVW_ELEMS  = 768 * 256;
constexpr int    PROJW_ELEMS = 256 * 256;

__global__ __launch_bounds__(256) void build_cb_kernel(
    const float* __restrict__ bias_table, const float* __restrict__ mask,
    const int* __restrict__ rel_index, float* __restrict__ cb) {
  int idx = blockIdx.x * 256 + threadIdx.x;          // [64 w][8 h][64 m][64 j]
  int j = idx & 63, m = (idx >> 6) & 63, h = (idx >> 12) & 7, w = idx >> 15;
  float v = 0.f;
  if (j < N_TOK && m < N_TOK)
    v = bias_table[rel_index[m * 49 + j] * 8 + h] + mask[(w * 49 + m) * 49 + j];
  cb[idx] = v;
}

__global__ __launch_bounds__(256) void cvt_w_kernel(
    const float* __restrict__ qkv_w, const float* __restrict__ proj_w,
    bf16* __restrict__ qkv_wb, bf16* __restrict__ proj_wb) {
  int i = blockIdx.x * 256 + threadIdx.x;
  if (i < QKVW_ELEMS) qkv_wb[i] = (bf16)qkv_w[i];
  else                proj_wb[i - QKVW_ELEMS] = (bf16)proj_w[i - QKVW_ELEMS];
}

__global__ __launch_bounds__(512, 4) void win_attn_kernel(
    const float* __restrict__ x, const bf16* __restrict__ qkv_wb,
    const float* __restrict__ qkv_b, const bf16* __restrict__ proj_wb,
    const float* __restrict__ proj_b, const float* __restrict__ cb,
    float* __restrict__ out) {
  __shared__ bf16 smem[SMEM_ELEMS];

  const int beta  = blockIdx.x;
  const int w_idx = beta >> 6;          // 64 consecutive blocks share one mask slice
  const int img   = beta & 63;
  const int b     = img * 64 + w_idx;
  const int tid   = threadIdx.x;
  const int wv    = tid >> 6;           // wave id; also head id in stage 2
  const int l     = tid & 63;
  const int l15   = l & 15, lgp = l >> 4;

  const f32x4 fzero = {0.f, 0.f, 0.f, 0.f};

  // zero pad + vT cols j in [49,56) of rows 224..255 (bytes not covered by
  // fresh XB writes; everything else in vT zone is finite by construction)
  if (tid < 512) smem[PAD_BASE + tid] = (bf16)0.f;
  if (tid < 224) {
    int d = 224 + tid / 7, j = 49 + tid % 7;
    smem[VT + d * 56 + j] = (bf16)0.f;
  }

  // ---------------- stage 0: x tile f32 -> XB (bf16, swizzled, over vT) ----
  const float* xg = x + (size_t)b * (N_TOK * DIM_C);
  for (int c = tid; c < (N_TOK * DIM_C / 8); c += 512) {
    int m = c >> 5, k0 = (c & 31) * 8;
    f32x8 f = *reinterpret_cast<const f32x8*>(xg + m * 256 + k0);
    bf16x8 v;
#pragma unroll
    for (int e = 0; e < 8; ++e) v[e] = (bf16)f[e];
    *reinterpret_cast<bf16x8*>(&smem[VT + m * 256 + (k0 ^ ((m & 7) << 3))]) = v;
  }
  __syncthreads();

  // ---------------- stage 1a: Q,K (swapped: D[c rows, m cols]) -------------
  {
    f32x4 acc[4][4];   // [i c-tile][mt]
#pragma unroll
    for (int i = 0; i < 4; ++i)
      for (int mt = 0; mt < 4; ++mt) acc[i][mt] = fzero;
    for (int k0 = 0; k0 < 8; ++k0) {
      const int kk = k0 * 32 + lgp * 8;
      bf16x8 XBf[4];                      // B-frags: lane l15 = token col m
#pragma unroll
      for (int mt = 0; mt < 4; ++mt) {
        int m = mt * 16 + l15; int mc = m < N_TOK ? m : 48;
        XBf[mt] = *reinterpret_cast<const bf16x8*>(
            &smem[VT + mc * 256 + (kk ^ ((mc & 7) << 3))]);
      }
#pragma unroll
      for (int i = 0; i < 4; ++i) {
        int c = (4 * wv + i) * 16 + l15;  // A-frag: lane l15 = c row
        bf16x8 Aw = *reinterpret_cast<const bf16x8*>(qkv_wb + c * DIM_C + kk);
#pragma unroll
        for (int mt = 0; mt < 4; ++mt) acc[i][mt] = MFMA16(Aw, XBf[mt], acc[i][mt]);
      }
    }
#pragma unroll
    for (int i = 0; i < 4; ++i) {
      int ct = 4 * wv + i;
      int c0 = ct * 16 + lgp * 4;
      f32x4 qb = *reinterpret_cast<const f32x4*>(qkv_b + c0);
      float sc = (ct < 16) ? SCALE : 1.0f;
#pragma unroll
      for (int mt = 0; mt < 4; ++mt) {
        int m = mt * 16 + l15;
        if (m < N_TOK) {
          float v0 = (acc[i][mt][0] + qb[0]) * sc;
          float v1 = (acc[i][mt][1] + qb[1]) * sc;
          float v2 = (acc[i][mt][2] + qb[2]) * sc;
          float v3 = (acc[i][mt][3] + qb[3]) * sc;
          int base = m * 512 + (c0 ^ ((m & 7) << 3));
          *reinterpret_cast<bf16x2*>(&smem[base])     = bf16x2{(bf16)v0, (bf16)v1};
          *reinterpret_cast<bf16x2*>(&smem[base + 2]) = bf16x2{(bf16)v2, (bf16)v3};
        }
      }
    }
  }

  // ---------------- stage 1b: V (unswapped: D[m rows, dd cols]) ------------
  {
    f32x4 accv[2][4];  // [i][mt]
#pragma unroll
    for (int i = 0; i < 2; ++i)
      for (int mt = 0; mt < 4; ++mt) accv[i][mt] = fzero;
    for (int k0 = 0; k0 < 8; ++k0) {
      const int kk = k0 * 32 + lgp * 8;
      bf16x8 XA[4];                       // A-frags: lane l15 = token row m
#pragma unroll
      for (int mt = 0; mt < 4; ++mt) {
        int m = mt * 16 + l15; int mc = m < N_TOK ? m : 48;
        XA[mt] = *reinterpret_cast<const bf16x8*>(
            &smem[VT + mc * 256 + (kk ^ ((mc & 7) << 3))]);
      }
#pragma unroll
      for (int i = 0; i < 2; ++i) {
        int c = (32 + 2 * wv + i) * 16 + l15;  // B-frag: lane l15 = col c
        bf16x8 Bw = *reinterpret_cast<const bf16x8*>(qkv_wb + c * DIM_C + kk);
#pragma unroll
        for (int mt = 0; mt < 4; ++mt) accv[i][mt] = MFMA16(XA[mt], Bw, accv[i][mt]);
      }
    }
    __syncthreads();   // all XB reads done; vT zone may be overwritten
#pragma unroll
    for (int i = 0; i < 2; ++i) {
      int dd = (2 * wv + i) * 16 + l15;
      float qb = qkv_b[512 + dd];
#pragma unroll
      for (int mt = 0; mt < 4; ++mt) {
#pragma unroll
        for (int r = 0; r < 4; ++r) {
          int m = mt * 16 + lgp * 4 + r;
          if (m < N_TOK) smem[VT + dd * 56 + m] = (bf16)(accv[i][mt][r] + qb);
        }
      }
    }
  }
  __syncthreads();

  // ---------------- stage 2 (wave = head h): S^T, softmax, PV --------------
  const int h = wv;
  {
    // V^T fragments (A-side of swapped PV)
    bf16x8 Vf[2][2];
#pragma unroll
    for (int dt = 0; dt < 2; ++dt)
#pragma unroll
      for (int ks = 0; ks < 2; ++ks) {
        int d = h * 32 + dt * 16 + l15;
        Vf[dt][ks] = *reinterpret_cast<const bf16x8*>(
            &smem[VT + d * 56 + ks * 32 + lgp * 8]);
      }
    // K fragments (A-side of S^T): lane l15 = key row j
    bf16x8 Ak[4];
#pragma unroll
    for (int jt = 0; jt < 4; ++jt) {
      int j = jt * 16 + l15; int jr = j < N_TOK ? j : 48;
      Ak[jt] = *reinterpret_cast<const bf16x8*>(
          &smem[jr * 512 + ((256 + h * 32 + lgp * 8) ^ ((jr & 7) << 3))]);
    }
    const float* cbp = cb + ((size_t)(w_idx * 8 + h)) * 4096;

#pragma unroll
    for (int mt = 0; mt < 4; ++mt) {
      int mrow = mt * 16 + l15;
      int mc = mrow < N_TOK ? mrow : 48;
      bf16x8 Bq = *reinterpret_cast<const bf16x8*>(
          &smem[mc * 512 + ((h * 32 + lgp * 8) ^ ((mc & 7) << 3))]);
      f32x4 s4[4];
#pragma unroll
      for (int jt = 0; jt < 4; ++jt) s4[jt] = MFMA16(Ak[jt], Bq, fzero);

      float e[4][4];
#pragma unroll
      for (int jt = 0; jt < 4; ++jt) {
        f32x4 cb4 = *reinterpret_cast<const f32x4*>(
            cbp + mrow * 64 + jt * 16 + lgp * 4);
#pragma unroll
        for (int r = 0; r < 4; ++r) {
          float v = s4[jt][r] + cb4[r];
          if (jt == 3) {                       // j = 48 + lgp*4 + r ; keep only j=48
            if (r == 0) v = (lgp == 0) ? v : -3.0e38f;
            else        v = -3.0e38f;
          }
          e[jt][r] = v;
        }
      }
      // register-tree max over 16, then across the 4 lane-replicas of this m
      float mx = e[0][0];
#pragma unroll
      for (int jt = 0; jt < 4; ++jt)
#pragma unroll
        for (int r = 0; r < 4; ++r) mx = fmaxf(mx, e[jt][r]);
      mx = fmaxf(mx, __shfl_xor(mx, 16));
      mx = fmaxf(mx, __shfl_xor(mx, 32));
      float sum = 0.f;
#pragma unroll
      for (int jt = 0; jt < 4; ++jt)
#pragma unroll
        for (int r = 0; r < 4; ++r) {
          float ex = __expf(e[jt][r] - mx);
          e[jt][r] = ex;
          sum += ex;
        }
      sum += __shfl_xor(sum, 16);
      sum += __shfl_xor(sum, 32);
      float rinv = 1.0f / sum;

      // P[m][j] (unnormalized, zeros at j>=49) into dead Q/K stripes
      if (mrow < N_TOK) {
#pragma unroll
        for (int jt = 0; jt < 4; ++jt) {
          int jc0 = jt * 16 + lgp * 4;
          int cc  = (jt < 2) ? (h * 32 + jc0) : (224 + h * 32 + jc0);
          int base = mrow * 512 + (cc ^ ((mrow & 7) << 3));
          *reinterpret_cast<bf16x2*>(&smem[base]) =
              bf16x2{(bf16)e[jt][0], (bf16)e[jt][1]};
          *reinterpret_cast<bf16x2*>(&smem[base + 2]) =
              bf16x2{(bf16)e[jt][2], (bf16)e[jt][3]};
        }
      }
      // PV (swapped): D[d rows, m cols] = V^T . P^T
      f32x4 pv[2] = {fzero, fzero};
#pragma unroll
      for (int ks = 0; ks < 2; ++ks) {
        int j0 = ks * 32 + lgp * 8;
        int cc = ((ks == 0) ? (h * 32) : (224 + h * 32)) + j0;
        bf16x8 Bp = *reinterpret_cast<const bf16x8*>(
            &smem[mc * 512 + (cc ^ ((mc & 7) << 3))]);
#pragma unroll
        for (int dt = 0; dt < 2; ++dt) pv[dt] = MFMA16(Vf[dt][ks], Bp, pv[dt]);
      }
      // ao[m][d] into this head's K-stripe (col 256+32h+d), normalized
      if (mrow < N_TOK) {
#pragma unroll
        for (int dt = 0; dt < 2; ++dt) {
          float a0 = pv[dt][0] * rinv, a1 = pv[dt][1] * rinv;
          float a2 = pv[dt][2] * rinv, a3 = pv[dt][3] * rinv;
          int cc0 = 256 + h * 32 + dt * 16 + lgp * 4;
          int base = mrow * 512 + (cc0 ^ ((mrow & 7) << 3));
          *reinterpret_cast<bf16x2*>(&smem[base])     = bf16x2{(bf16)a0, (bf16)a1};
          *reinterpret_cast<bf16x2*>(&smem[base + 2]) = bf16x2{(bf16)a2, (bf16)a3};
        }
      }
    }
  }
  __syncthreads();

  // ---------------- stage 3: out^T = proj_w . ao^T (swapped) ---------------
  f32x4 acc2[2][4];
#pragma unroll
  for (int ci = 0; ci < 2; ++ci)
    for (int mt = 0; mt < 4; ++mt) acc2[ci][mt] = fzero;
  for (int k0 = 0; k0 < 8; ++k0) {
    const int kk = k0 * 32 + lgp * 8;
    bf16x8 Bao[4];                        // B-frags: lane l15 = token col m
#pragma unroll
    for (int mt = 0; mt < 4; ++mt) {
      int m = mt * 16 + l15; int mc = m < N_TOK ? m : 48;
      Bao[mt] = *reinterpret_cast<const bf16x8*>(
          &smem[mc * 512 + ((256 + kk) ^ ((mc & 7) << 3))]);
    }
#pragma unroll
    for (int ci = 0; ci < 2; ++ci) {
      int c = (2 * wv + ci) * 16 + l15;   // A-frag: lane l15 = c row
      bf16x8 Aw = *reinterpret_cast<const bf16x8*>(proj_wb + c * DIM_C + kk);
#pragma unroll
      for (int mt = 0; mt < 4; ++mt) acc2[ci][mt] = MFMA16(Aw, Bao[mt], acc2[ci][mt]);
    }
  }
  float* ob = out + (size_t)b * (N_TOK * DIM_C);
#pragma unroll
  for (int ci = 0; ci < 2; ++ci) {
    int c0 = (2 * wv + ci) * 16 + lgp * 4;
    f32x4 pb = *reinterpret_cast<const f32x4*>(proj_b + c0);
#pragma unroll
    for (int mt = 0; mt < 4; ++mt) {
      int mrow = mt * 16 + l15;
      if (mrow < N_TOK) {
        f32x4 o;
#pragma unroll
        for (int r = 0; r < 4; ++r) o[r] = acc2[ci][mt][r] + pb[r];
        *reinterpret_cast<f32x4*>(ob + mrow * 256 + c0) = o;
      }
    }
  }
}

extern "C" void kernel_launch(void* const* d_in, const int* in_sizes, int n_in,
                              void* d_out, int out_size, void* d_ws, size_t ws_size,
                              hipStream_t stream) {
  const float* x          = (const float*)d_in[0];
  const float* mask       = (const float*)d_in[1];
  const float* qkv_w      = (const float*)d_in[2];
  const float* qkv_b      = (const float*)d_in[3];
  const float* proj_w     = (const float*)d_in[4];
  const float* proj_b     = (const float*)d_in[5];
  const float* bias_table = (const float*)d_in[6];
  const int*   rel_index  = (const int*)d_in[7];

  float* cb      = (float*)d_ws;
  bf16*  qkv_wb  = (bf16*)((char*)d_ws + CB_BYTES);
  bf16*  proj_wb = (bf16*)((char*)d_ws + CB_BYTES + QKVW_ELEMS * 2);

  hipLaunchKernelGGL(build_cb_kernel, dim3(8192), dim3(256), 0, stream,
                     bias_table, mask, rel_index, cb);
  hipLaunchKernelGGL(cvt_w_kernel, dim3(1024), dim3(256), 0, stream,
                     qkv_w, proj_w, qkv_wb, proj_wb);
  hipLaunchKernelGGL(win_attn_kernel, dim3(4096), dim3(512), 0, stream,
                     x, qkv_wb, qkv_b, proj_wb, proj_b, cb, (float*)d_out);
}